// Round 1
// baseline (13766.005 us; speedup 1.0000x reference)
//
#include <hip/hip_runtime.h>

// LSTM T=1000 N=32 D=320 H=1024 L=3 on MI355X.
// Wavefront over (layer,t); one kernel launch per wave (launch = grid sync).
// bf16 MFMA 16x16x32; weights pre-packed into B-fragment order in d_ws.
//
// ws layout (bytes):
//   [0,         20480000)  x as bf16            (T*N*320)
//   [20480000,  65044480)  packed B fragments   (22,282,240 bf16)
//   [65044480,  65437696)  h ping-pong bf16     (L * 2 * N*H)
//   [65437696,  65830912)  c state fp32         (L * N*H)
//   [65830912,  65880064)  bias fp32            (L * 4096)

#define T_ 1000
#define N_ 32
#define D_ 320
#define H_ 1024
#define NH (N_ * H_)

typedef __bf16 bf16;
typedef bf16 bf16x8 __attribute__((ext_vector_type(8)));
typedef bf16 bf16x4 __attribute__((ext_vector_type(4)));
typedef float floatx4 __attribute__((ext_vector_type(4)));

__device__ __forceinline__ float sigm(float x) { return 1.f / (1.f + __expf(-x)); }
__device__ __forceinline__ float tanh_(float x) {
  float e = __expf(2.f * x);
  return 1.f - 2.f / (e + 1.f);
}

// ---- prep: x (fp32) -> bf16 ----
__global__ __launch_bounds__(256) void prep_x(const float4* __restrict__ x,
                                              bf16x4* __restrict__ xb) {
  int idx = blockIdx.x * 256 + threadIdx.x;  // 2,560,000 threads, 4 elems each
  float4 v = x[idx];
  bf16x4 o;
  o[0] = (bf16)v.x; o[1] = (bf16)v.y; o[2] = (bf16)v.z; o[3] = (bf16)v.w;
  xb[idx] = o;
}

// ---- prep: pack W = [w_ih_l ; w_hh_l] (K x 4096) into MFMA B-fragment order.
// packed idx (within layer) = ((g*64 + jt)*KB + kb)*512 + lane*8 + i
//   k = kb*32 + (lane>>4)*8 + i ; j = g*1024 + jt*16 + (lane&15)
__global__ __launch_bounds__(256) void prep_pack(const float* __restrict__ w_ih0,
                                                 const float* __restrict__ w_ihr,
                                                 const float* __restrict__ w_hh,
                                                 bf16* __restrict__ packed) {
  int idx = blockIdx.x * 256 + threadIdx.x;  // 22,282,240 total
  int l, r;
  if (idx < 5505024)       { l = 0; r = idx; }
  else if (idx < 13893632) { l = 1; r = idx - 5505024; }
  else                     { l = 2; r = idx - 13893632; }
  const int i    = r & 7;
  const int lane = (r >> 3) & 63;
  const int q    = r >> 9;
  int kb, p;
  if (l == 0) { kb = q % 42; p = q / 42; }   // KB=42 (10 x-blocks + 32 h-blocks)
  else        { kb = q & 63; p = q >> 6; }   // KB=64 (32 + 32)
  const int jt = p & 63;
  const int g  = p >> 6;
  const int k  = kb * 32 + ((lane >> 4) << 3) + i;
  const int j  = (g << 10) + jt * 16 + (lane & 15);
  const int KX = (l == 0) ? 320 : 1024;
  float v;
  if (k < KX) {
    v = (l == 0) ? w_ih0[(size_t)k * 4096 + j]
                 : w_ihr[(size_t)(l - 1) * 4194304 + (size_t)k * 4096 + j];
  } else {
    v = w_hh[(size_t)l * 4194304 + (size_t)(k - KX) * 4096 + j];
  }
  packed[idx] = (bf16)v;
}

// ---- prep: h0 -> hbuf slot 1 (t=0 reads slot (t-1)&1 == 1), c0 -> c_state, bias sum
__global__ __launch_bounds__(256) void prep_state(const float* __restrict__ h0,
                                                  const float* __restrict__ c0,
                                                  const float* __restrict__ b_ih,
                                                  const float* __restrict__ b_hh,
                                                  bf16* __restrict__ hbuf,
                                                  float* __restrict__ c_state,
                                                  float* __restrict__ bias) {
  int idx = blockIdx.x * 256 + threadIdx.x;  // 98,304 threads
  int l = idx >> 15;                         // NH = 32768
  int rem = idx & 32767;
  hbuf[(size_t)l * 2 * NH + NH + rem] = (bf16)h0[idx];
  c_state[idx] = c0[idx];
  if (idx < 12288) bias[idx] = b_ih[idx] + b_hh[idx];
}

// ---- one wavefront step: layer l at t = wv - l.
// grid = 192 blocks (3 layers x 64 j-tiles), 256 threads (4 waves, K-split).
__global__ __launch_bounds__(256) void lstm_step(int wv,
                                                 const bf16* __restrict__ xb,
                                                 const bf16* __restrict__ packed,
                                                 bf16* __restrict__ hbuf,
                                                 float* __restrict__ c_state,
                                                 const float* __restrict__ bias,
                                                 float* __restrict__ out) {
  const int l  = blockIdx.x >> 6;
  const int jt = blockIdx.x & 63;
  const int t  = wv - l;
  if (t < 0 || t >= T_) return;

  const int tid  = threadIdx.x;
  const int wid  = tid >> 6;
  const int lane = tid & 63;
  const int quad = lane >> 4;
  const int lo   = lane & 15;

  const int KB   = (l == 0) ? 42 : 64;
  const int KXb  = (l == 0) ? 10 : 32;
  const int xstr = (l == 0) ? D_ : H_;
  const bf16* xsrc = (l == 0) ? (xb + (size_t)t * (N_ * D_))
                              : (hbuf + (size_t)(l - 1) * 2 * NH + (size_t)(t & 1) * NH);
  const bf16* hsrc = hbuf + (size_t)l * 2 * NH + (size_t)((t - 1) & 1) * NH;
  const size_t lbase = (l == 0) ? 0 : (l == 1 ? 5505024u : 13893632u);
  const int gstr = 64 * KB * 512;                 // per-gate stride (elements)
  const bf16* Bb = packed + lbase + (size_t)jt * KB * 512;

  floatx4 acc[2][4];
  const floatx4 zero = {0.f, 0.f, 0.f, 0.f};
#pragma unroll
  for (int mt = 0; mt < 2; ++mt)
#pragma unroll
    for (int g = 0; g < 4; ++g) acc[mt][g] = zero;

  const int arow0 = lo * xstr + quad * 8;
  const int arow1 = (16 + lo) * xstr + quad * 8;
  const int hrow0 = lo * H_ + quad * 8;
  const int hrow1 = (16 + lo) * H_ + quad * 8;

#pragma unroll 2
  for (int kb = wid; kb < KB; kb += 4) {
    bf16x8 a0, a1;
    if (kb < KXb) {
      const bf16* p = xsrc + kb * 32;
      a0 = *(const bf16x8*)(p + arow0);
      a1 = *(const bf16x8*)(p + arow1);
    } else {
      const bf16* p = hsrc + (kb - KXb) * 32;
      a0 = *(const bf16x8*)(p + hrow0);
      a1 = *(const bf16x8*)(p + hrow1);
    }
    const bf16* bp = Bb + kb * 512 + lane * 8;
    bf16x8 b0 = *(const bf16x8*)(bp);
    bf16x8 b1 = *(const bf16x8*)(bp + gstr);
    bf16x8 b2 = *(const bf16x8*)(bp + 2 * gstr);
    bf16x8 b3 = *(const bf16x8*)(bp + 3 * gstr);
    acc[0][0] = __builtin_amdgcn_mfma_f32_16x16x32_bf16(a0, b0, acc[0][0], 0, 0, 0);
    acc[0][1] = __builtin_amdgcn_mfma_f32_16x16x32_bf16(a0, b1, acc[0][1], 0, 0, 0);
    acc[0][2] = __builtin_amdgcn_mfma_f32_16x16x32_bf16(a0, b2, acc[0][2], 0, 0, 0);
    acc[0][3] = __builtin_amdgcn_mfma_f32_16x16x32_bf16(a0, b3, acc[0][3], 0, 0, 0);
    acc[1][0] = __builtin_amdgcn_mfma_f32_16x16x32_bf16(a1, b0, acc[1][0], 0, 0, 0);
    acc[1][1] = __builtin_amdgcn_mfma_f32_16x16x32_bf16(a1, b1, acc[1][1], 0, 0, 0);
    acc[1][2] = __builtin_amdgcn_mfma_f32_16x16x32_bf16(a1, b2, acc[1][2], 0, 0, 0);
    acc[1][3] = __builtin_amdgcn_mfma_f32_16x16x32_bf16(a1, b3, acc[1][3], 0, 0, 0);
  }

  // K-split reduction across the 4 waves.
  __shared__ float red[4][2][4][4][64];
#pragma unroll
  for (int mt = 0; mt < 2; ++mt)
#pragma unroll
    for (int g = 0; g < 4; ++g)
#pragma unroll
      for (int r = 0; r < 4; ++r) red[wid][mt][g][r][lane] = acc[mt][g][r];
  __syncthreads();
  if (wid != 0) return;

  // epilogue on wave 0: all four gates for (m, j_h) live in the same lane/reg.
  const int j_h = jt * 16 + lo;
  const float bI = bias[l * 4096 + j_h];
  const float bF = bias[l * 4096 + 1024 + j_h];
  const float bG = bias[l * 4096 + 2048 + j_h];
  const float bO = bias[l * 4096 + 3072 + j_h];
  float* cst = c_state + l * NH;
  bf16* hdst = hbuf + (size_t)l * 2 * NH + (size_t)(t & 1) * NH;

#pragma unroll
  for (int mt = 0; mt < 2; ++mt)
#pragma unroll
    for (int r = 0; r < 4; ++r) {
      const int m = mt * 16 + quad * 4 + r;
      float s0 = 0.f, s1 = 0.f, s2 = 0.f, s3 = 0.f;
#pragma unroll
      for (int w2 = 0; w2 < 4; ++w2) {
        s0 += red[w2][mt][0][r][lane];
        s1 += red[w2][mt][1][r][lane];
        s2 += red[w2][mt][2][r][lane];
        s3 += red[w2][mt][3][r][lane];
      }
      const float ii = sigm(s0 + bI);
      const float ff = sigm(s1 + bF);
      const float gg = tanh_(s2 + bG);
      const float oo = sigm(s3 + bO);
      const int off = m * H_ + j_h;
      const float c = ff * cst[off] + ii * gg;
      cst[off] = c;
      const float h = oo * tanh_(c);
      hdst[off] = (bf16)h;
      if (l == 2) out[(size_t)t * NH + off] = h;
      if (t == T_ - 1) {
        out[32768000 + l * NH + off] = h;   // hT (fp32, pre-rounding)
        out[32866304 + l * NH + off] = c;   // cT
      }
    }
}

extern "C" void kernel_launch(void* const* d_in, const int* in_sizes, int n_in,
                              void* d_out, int out_size, void* d_ws, size_t ws_size,
                              hipStream_t stream) {
  (void)in_sizes; (void)n_in; (void)out_size; (void)ws_size;
  const float* x     = (const float*)d_in[0];
  const float* h0    = (const float*)d_in[1];
  const float* c0    = (const float*)d_in[2];
  const float* w_ih0 = (const float*)d_in[3];
  const float* w_ihr = (const float*)d_in[4];
  const float* w_hh  = (const float*)d_in[5];
  const float* b_ih  = (const float*)d_in[6];
  const float* b_hh  = (const float*)d_in[7];
  float* out = (float*)d_out;
  char* ws = (char*)d_ws;

  bf16*  xb      = (bf16*)(ws + 0);
  bf16*  packed  = (bf16*)(ws + 20480000);
  bf16*  hbuf    = (bf16*)(ws + 65044480);
  float* c_state = (float*)(ws + 65437696);
  float* bias    = (float*)(ws + 65830912);

  hipLaunchKernelGGL(prep_x, dim3(10000), dim3(256), 0, stream,
                     (const float4*)x, (bf16x4*)xb);
  hipLaunchKernelGGL(prep_pack, dim3(87040), dim3(256), 0, stream,
                     w_ih0, w_ihr, w_hh, packed);
  hipLaunchKernelGGL(prep_state, dim3(384), dim3(256), 0, stream,
                     h0, c0, b_ih, b_hh, hbuf, c_state, bias);
  for (int wv = 0; wv < T_ + 2; ++wv)
    hipLaunchKernelGGL(lstm_step, dim3(192), dim3(256), 0, stream, wv,
                       (const bf16*)xb, (const bf16*)packed, hbuf, c_state, bias, out);
}